// Round 19
// baseline (114.269 us; speedup 1.0000x reference)
//
#include <hip/hip_runtime.h>
#include <hip/hip_bf16.h>
#include <stdint.h>

#define BDIM 32
#define SDIM 4096
#define SP1  4097
#define EDIM 256
#define FDIM 256
#define LDIM 50
#define TTILE 128
#define NT    32   // 32 tiles x 128 = 4096; t=4096 computed by special blocks in prep stage
#define NWB   1024 // weight-prep blocks
#define NSB   1908 // streaming blocks (ceil(30522*256/16/256))

typedef __attribute__((ext_vector_type(8))) short bf16x8v;
typedef __attribute__((ext_vector_type(4))) float f32x4;

__device__ __forceinline__ unsigned short f2bf(float f) {
    union { float f; uint32_t u; } v; v.f = f;
    uint32_t u = v.u;
    uint32_t r = (u + 0x7fffu + ((u >> 16) & 1u)) >> 16;
    return (unsigned short)r;
}

// tanh(x) = 1 - 2/(1+e^{2x}); v_rcp_f32 (~1ulp) is plenty vs bf16 storage noise.
__device__ __forceinline__ float tanh_fast(float x) {
    float e = __expf(2.0f * x);
    float r = __builtin_amdgcn_rcpf(e + 1.0f);
    return fmaf(-2.0f, r, 1.0f);
}

// Scalar casts -> compiler emits v_cvt_pk_bf16_f32 (m240: don't hand-write).
__device__ __forceinline__ uint32_t pack_bf2(float lo, float hi) {
    union { __hip_bfloat162 v; uint32_t u; } cv;
    cv.v = __halves2bfloat162(__float2bfloat16(lo), __float2bfloat16(hi));
    return cv.u;
}

__device__ __forceinline__ void load_lds16(const void* g, uint32_t* l) {
    __builtin_amdgcn_global_load_lds(
        (const __attribute__((address_space(1))) uint32_t*)g,
        (__attribute__((address_space(3))) uint32_t*)l, 16, 0, 0);
}

// ---- Single prep kernel. Blocks (dispatch order):
//      [0,32)            : t=4096 specials — fp32 conv_w direct, 8 lanes/filter-row
//      [32, 32+NWB)      : Wb2[g][hi4][f][8] bf16, W2k, zero page
//      [32+NWB, +NSB)    : embb fp32->bf16 streaming (16 elems/thread)
//      All branches independent -> no intra-kernel ordering needed. ----
__global__ __launch_bounds__(256) void prep_all(
    const float* __restrict__ emb, const int* __restrict__ ids,
    const float* __restrict__ conv_w, const float* __restrict__ conv_b,
    const float* __restrict__ U_w, const float* __restrict__ final_w,
    unsigned short* __restrict__ embb, unsigned short* __restrict__ Wb2,
    unsigned short* __restrict__ W2k, uint32_t* __restrict__ zp,
    float* __restrict__ part)
{
    const int tid = threadIdx.x;
    const int idx = blockIdx.x;

    if (idx < BDIM) {
        // ---- special: position t=4096 for batch b=idx (fp32 weights, cooperative) ----
        __shared__ float x0[256], x1[256], hsh[256], red[256];
        const int b = idx;
        {
            int id0 = ids[b * SDIM + 4094];
            int id1 = ids[b * SDIM + 4095];
            x0[tid] = emb[(size_t)id0 * EDIM + tid];
            x1[tid] = emb[(size_t)id1 * EDIM + tid];
        }
        __syncthreads();

        // H[4096][f] = sum_e w[f,e,0]*x0[e] + w[f,e,1]*x1[e]
        // thread: f = pass*32 + tid/8, e-chunk = (tid&7)*32 .. +32 (contig float4 stream)
        const int sub = tid & 7;
        #pragma unroll 1
        for (int pass = 0; pass < 8; ++pass) {
            int f = pass * 32 + (tid >> 3);
            const float4* row = (const float4*)(conv_w + (size_t)f * 1024 + sub * 128);
            float a = 0.f;
            #pragma unroll
            for (int i = 0; i < 32; ++i) {
                float4 v = row[i];
                int e = sub * 32 + i;
                a = fmaf(v.x, x0[e], fmaf(v.y, x1[e], a));
            }
            red[tid] = a;
            __syncthreads();
            if (tid < 32) {
                float s = 0.f;
                #pragma unroll
                for (int j = 0; j < 8; ++j) s += red[tid * 8 + j];
                int f2 = pass * 32 + tid;
                hsh[f2] = tanh_fast(conv_b[f2] + s);
            }
            __syncthreads();
        }

        // scores/t for 50 labels: (label, f-chunk) split, float4 loads.
        float sc = 0.f, tv = 0.f;
        {
            const int l = tid & 63, c = tid >> 6;
            if (l < LDIM) {
                const float4* uw = (const float4*)(U_w + (size_t)l * FDIM + c * 64);
                const float4* fw = (const float4*)(final_w + (size_t)l * FDIM + c * 64);
                const float4* hh = (const float4*)(hsh + c * 64);
                #pragma unroll
                for (int i = 0; i < 16; ++i) {
                    float4 h = hh[i], u = uw[i], w = fw[i];
                    sc = fmaf(h.x, u.x, fmaf(h.y, u.y, fmaf(h.z, u.z, fmaf(h.w, u.w, sc))));
                    tv = fmaf(h.x, w.x, fmaf(h.y, w.y, fmaf(h.z, w.z, fmaf(h.w, w.w, tv))));
                }
            }
        }
        red[tid] = sc;
        __syncthreads();
        float sc4 = (tid < 64) ? red[tid] + red[tid + 64] + red[tid + 128] + red[tid + 192] : 0.f;
        __syncthreads();
        red[tid] = tv;
        __syncthreads();
        if (tid < LDIM) {
            float tv4 = red[tid] + red[tid + 64] + red[tid + 128] + red[tid + 192];
            size_t o = (((size_t)b * (NT + 1) + NT) * LDIM + tid) * 3;
            part[o] = sc4; part[o + 1] = 1.0f; part[o + 2] = tv4;
        }
    } else if (idx < BDIM + NWB) {
        // ---- weights: Wb2 [g][hi4][f][8] (kk=k*256+e), W2k, zero page ----
        int o = (idx - BDIM) * 256 + tid;            // o < 262144
        {
            int kk = o & 1023, f = o >> 10;
            int e = kk & 255, k = kk >> 8;
            int g = kk >> 5, h4 = (kk >> 3) & 3, j = kk & 7;
            Wb2[((size_t)(g * 4 + h4) * 256 + f) * 8 + j] = f2bf(conv_w[f * 1024 + e * 4 + k]);
        }
        if (o < 32768) {
            int j = o & 7, c = (o >> 3) & 127, g = o >> 10;
            int k = g * 8 + j, l = c & 63;
            float v = 0.f;
            if (l < LDIM) v = (c < 64) ? U_w[l * FDIM + k] : final_w[l * FDIM + k];
            W2k[o] = f2bf(v);
        }
        if (o < 128) zp[o] = 0;
    } else {
        // ---- streaming: embedding table fp32 -> bf16, 16 elems/thread ----
        size_t o = ((size_t)(idx - BDIM - NWB) * 256 + tid) * 16;
        if (o < (size_t)30522 * 256) {
            float4 v0 = *(const float4*)(emb + o);
            float4 v1 = *(const float4*)(emb + o + 4);
            float4 v2 = *(const float4*)(emb + o + 8);
            float4 v3 = *(const float4*)(emb + o + 12);
            union { unsigned short u[8]; uint4 q; } pa, pb;
            pa.u[0] = f2bf(v0.x); pa.u[1] = f2bf(v0.y); pa.u[2] = f2bf(v0.z); pa.u[3] = f2bf(v0.w);
            pa.u[4] = f2bf(v1.x); pa.u[5] = f2bf(v1.y); pa.u[6] = f2bf(v1.z); pa.u[7] = f2bf(v1.w);
            pb.u[0] = f2bf(v2.x); pb.u[1] = f2bf(v2.y); pb.u[2] = f2bf(v2.z); pb.u[3] = f2bf(v2.w);
            pb.u[4] = f2bf(v3.x); pb.u[5] = f2bf(v3.y); pb.u[6] = f2bf(v3.z); pb.u[7] = f2bf(v3.w);
            *(uint4*)(embb + o)     = pa.q;
            *(uint4*)(embb + o + 8) = pb.q;
        }
    }
}

// ---- Fused (best-known R10 structure): gather -> conv1d+tanh -> scores|t GEMM -> partials ----
__global__ __launch_bounds__(256, 2) void fused_kernel(
    const int* __restrict__ ids, const unsigned short* __restrict__ embb,
    const unsigned short* __restrict__ Wb2, const float* __restrict__ conv_b,
    const unsigned short* __restrict__ W2k, const uint32_t* __restrict__ zp,
    float* __restrict__ part)
{
    __shared__ uint32_t xs[132 * 128];   // 67,584 B: x rows 0..130, reused as H-tile

    const int tid  = threadIdx.x;
    const int lane = tid & 63;
    const int wid  = tid >> 6;
    const int b    = blockIdx.y;
    const int tile = blockIdx.x;
    const int t0   = tile * TTILE;
    const int l15  = lane & 15;
    const int hi4  = lane >> 4;
    const int q    = lane & 31;
    const int half = lane >> 5;

    // ---- stage rows 0..130 (p = t0-2+r): all ids first, then all gathers ----
    {
        int nid[17];
        #pragma unroll
        for (int j = 0; j < 17; ++j) {
            int r0 = wid * 2 + j * 8;
            int r  = r0 + half;
            int p  = t0 - 2 + r;
            nid[j] = -1;
            if (r0 < 131 && r < 131 && (unsigned)p < SDIM)
                nid[j] = ids[b * SDIM + p];
        }
        const unsigned short* zs = (const unsigned short*)zp + q * 8;
        #pragma unroll
        for (int j = 0; j < 17; ++j) {
            int r0 = wid * 2 + j * 8;
            if (r0 >= 131) continue;                 // wave-uniform guard
            int r = r0 + half;
            const unsigned short* s = (nid[j] >= 0)
                ? embb + (size_t)nid[j] * EDIM + (((uint32_t)(q * 16) ^ ((uint32_t)(r & 7) << 4)) >> 1)
                : zs;
            load_lds16(s, &xs[r0 * 128]);
        }
    }
    __syncthreads();

    // ---- Conv GEMM: wave = 64 filters (M) x 128 positions (N), K=1024 ----
    const int fbase = wid * 64;
    const unsigned short* afbase = Wb2 + (size_t)(hi4 * 256 + fbase + l15) * 8;

    f32x4 acc[4][8];
    #pragma unroll
    for (int a = 0; a < 4; ++a)
        #pragma unroll
        for (int n = 0; n < 8; ++n) acc[a][n] = (f32x4){0.f, 0.f, 0.f, 0.f};

    bf16x8v afc[4];
    #pragma unroll
    for (int a = 0; a < 4; ++a) afc[a] = *(const bf16x8v*)(afbase + a * 128);   // g=0

    #pragma unroll 1
    for (int k = 0; k < 4; ++k) {
        uint32_t bb[8];
        #pragma unroll
        for (int n = 0; n < 8; ++n) {
            int r = n * 16 + l15 + k;
            bb[n] = (uint32_t)(r * 512) ^ (uint32_t)(hi4 * 16) ^ (uint32_t)((r & 7) << 4);
        }
        const unsigned short* afg = afbase + (size_t)k * 65536;
        #pragma unroll
        for (int es = 0; es < 8; ++es) {
            // prefetch next g's A-fragments (always 4 loads in flight)
            const unsigned short* nxt = (es < 7)
                ? (afg + (size_t)(es + 1) * 8192)
                : (afbase + (size_t)((k + 1) & 3) * 65536);
            bf16x8v afn[4];
            #pragma unroll
            for (int a = 0; a < 4; ++a) afn[a] = *(const bf16x8v*)(nxt + a * 128);

            bf16x8v bfr[8];
            #pragma unroll
            for (int n = 0; n < 8; ++n)
                bfr[n] = *(const bf16x8v*)((const char*)xs + (bb[n] ^ (uint32_t)(es * 64)));

            __builtin_amdgcn_s_setprio(1);
            #pragma unroll
            for (int a = 0; a < 4; ++a)
                #pragma unroll
                for (int n = 0; n < 8; ++n)
                    acc[a][n] = __builtin_amdgcn_mfma_f32_16x16x32_bf16(afc[a], bfr[n], acc[a][n], 0, 0, 0);
            __builtin_amdgcn_s_setprio(0);

            #pragma unroll
            for (int a = 0; a < 4; ++a) afc[a] = afn[a];
        }
    }
    __syncthreads();   // all waves done reading xs

    // ---- tanh epilogue -> H-tile into LDS (same buffer), XOR-swizzled ----
    float4 cb[4];
    #pragma unroll
    for (int a = 0; a < 4; ++a)
        cb[a] = *(const float4*)(conv_b + fbase + a * 16 + hi4 * 4);
    #pragma unroll
    for (int n = 0; n < 8; ++n) {
        int tl = n * 16 + l15;
        uint32_t hb = (uint32_t)(tl * 512) ^ (uint32_t)(hi4 * 8)
                    ^ (uint32_t)(fbase * 2) ^ (uint32_t)((tl & 7) << 4);
        #pragma unroll
        for (int a = 0; a < 4; ++a) {
            f32x4 d = acc[a][n];
            uint2 pk;
            pk.x = pack_bf2(tanh_fast(d[0] + cb[a].x), tanh_fast(d[1] + cb[a].y));
            pk.y = pack_bf2(tanh_fast(d[2] + cb[a].z), tanh_fast(d[3] + cb[a].w));
            *(uint2*)((char*)xs + (hb ^ (uint32_t)(a * 32))) = pk;
        }
    }
    __syncthreads();

    // ---- P GEMM: 128 s-rows x 32 cols per wave (cbase..+15 scores, +64 t), K=256 ----
    const int cbase = wid * 16;
    f32x4 p2[8][2];
    #pragma unroll
    for (int m = 0; m < 8; ++m) { p2[m][0] = (f32x4){0,0,0,0}; p2[m][1] = (f32x4){0,0,0,0}; }

    uint32_t pb[8];
    #pragma unroll
    for (int m = 0; m < 8; ++m) {
        int sl = m * 16 + l15;
        pb[m] = (uint32_t)(sl * 512) ^ (uint32_t)(hi4 * 16) ^ (uint32_t)((sl & 7) << 4);
    }
    const unsigned short* wp0 = W2k + (size_t)(hi4 * 128 + cbase + l15) * 8;

    #pragma unroll
    for (int step = 0; step < 8; ++step) {
        bf16x8v ha[8], w2[2];
        #pragma unroll
        for (int m = 0; m < 8; ++m)
            ha[m] = *(const bf16x8v*)((const char*)xs + (pb[m] ^ (uint32_t)(step * 64)));
        w2[0] = *(const bf16x8v*)(wp0 + step * 4096);
        w2[1] = *(const bf16x8v*)(wp0 + 512 + step * 4096);
        __builtin_amdgcn_s_setprio(1);
        #pragma unroll
        for (int m = 0; m < 8; ++m) {
            p2[m][0] = __builtin_amdgcn_mfma_f32_16x16x32_bf16(ha[m], w2[0], p2[m][0], 0, 0, 0);
            p2[m][1] = __builtin_amdgcn_mfma_f32_16x16x32_bf16(ha[m], w2[1], p2[m][1], 0, 0, 0);
        }
        __builtin_amdgcn_s_setprio(0);
    }

    // ---- Lane-local online-softmax partials (all 128 rows valid) ----
    float mx = -1e30f;
    #pragma unroll
    for (int m = 0; m < 8; ++m)
        #pragma unroll
        for (int i = 0; i < 4; ++i)
            mx = fmaxf(mx, p2[m][0][i]);
    float se = 0.f, st = 0.f;
    #pragma unroll
    for (int m = 0; m < 8; ++m)
        #pragma unroll
        for (int i = 0; i < 4; ++i) {
            float e = __expf(p2[m][0][i] - mx);
            se += e;
            st += e * p2[m][1][i];
        }
    #pragma unroll
    for (int d = 16; d <= 32; d <<= 1) {
        float mo  = __shfl_xor(mx, d);
        float seo = __shfl_xor(se, d);
        float sto = __shfl_xor(st, d);
        float M  = fmaxf(mx, mo);
        float w0 = __expf(mx - M), w1 = __expf(mo - M);
        se = se * w0 + seo * w1;
        st = st * w0 + sto * w1;
        mx = M;
    }
    if (lane < 16) {
        int l = cbase + l15;
        if (l < LDIM) {
            size_t o = (((size_t)b * (NT + 1) + tile) * LDIM + l) * 3;
            part[o] = mx; part[o + 1] = se; part[o + 2] = st;
        }
    }
}

// ---- Final: merge 33 partial chunks -> logits ----
__global__ __launch_bounds__(64) void final_kernel(
    const float* __restrict__ part, const float* __restrict__ final_b,
    float* __restrict__ out)
{
    int b = blockIdx.x, l = threadIdx.x;
    if (l >= LDIM) return;
    float mx = -1e30f, se = 0.f, st = 0.f;
    for (int c = 0; c <= NT; ++c) {
        size_t o = (((size_t)b * (NT + 1) + c) * LDIM + l) * 3;
        float mo = part[o], seo = part[o + 1], sto = part[o + 2];
        float M  = fmaxf(mx, mo);
        float w0 = __expf(mx - M), w1 = __expf(mo - M);
        se = se * w0 + seo * w1;
        st = st * w0 + sto * w1;
        mx = M;
    }
    out[b * LDIM + l] = st / se + final_b[l];
}

extern "C" void kernel_launch(void* const* d_in, const int* in_sizes, int n_in,
                              void* d_out, int out_size, void* d_ws, size_t ws_size,
                              hipStream_t stream)
{
    const int*   ids     = (const int*)d_in[0];
    const float* emb     = (const float*)d_in[1];
    const float* conv_w  = (const float*)d_in[2];
    const float* conv_b  = (const float*)d_in[3];
    const float* U_w     = (const float*)d_in[4];
    const float* final_w = (const float*)d_in[5];
    const float* final_b = (const float*)d_in[6];

    char* ws = (char*)d_ws;
    size_t offE  = 0;
    size_t szE   = (size_t)30522 * 256 * 2;          // 15,627,264 B
    size_t offWb = offE + szE;
    size_t szWb  = 256 * 1024 * 2;                   // 524,288 B
    size_t offW2 = offWb + szWb;
    size_t szW2  = 32768 * 2;                        // 65,536 B
    size_t offZ  = offW2 + szW2;
    size_t szZ   = 512;
    size_t offP  = offZ + szZ;                       // 32*33*50*3 fp32 = 633,600 B

    unsigned short* embb = (unsigned short*)(ws + offE);
    unsigned short* Wb2  = (unsigned short*)(ws + offWb);
    unsigned short* W2k  = (unsigned short*)(ws + offW2);
    uint32_t*       zp   = (uint32_t*)(ws + offZ);
    float*          prt  = (float*)(ws + offP);

    prep_all<<<BDIM + NWB + NSB, 256, 0, stream>>>(emb, ids, conv_w, conv_b,
                                                   U_w, final_w, embb, Wb2, W2k, zp, prt);
    fused_kernel<<<dim3(NT, BDIM), 256, 0, stream>>>(ids, embb, Wb2, conv_b, W2k, zp, prt);
    final_kernel<<<BDIM, 64, 0, stream>>>(prt, final_b, (float*)d_out);
}

// Round 20
// 91.816 us; speedup vs baseline: 1.2445x; 1.2445x over previous
//
#include <hip/hip_runtime.h>
#include <hip/hip_bf16.h>
#include <stdint.h>

#define BDIM 32
#define SDIM 4096
#define SP1  4097
#define EDIM 256
#define FDIM 256
#define LDIM 50
#define TTILE 128
#define NT    32   // 32 tiles x 128 = 4096; t=4096 computed by special blocks in prep stage

typedef __attribute__((ext_vector_type(8))) short bf16x8v;
typedef __attribute__((ext_vector_type(4))) float f32x4;

__device__ __forceinline__ unsigned short f2bf(float f) {
    union { float f; uint32_t u; } v; v.f = f;
    uint32_t u = v.u;
    uint32_t r = (u + 0x7fffu + ((u >> 16) & 1u)) >> 16;
    return (unsigned short)r;
}

__device__ __forceinline__ float bf2f(unsigned short s) {
    union { uint32_t u; float f; } v; v.u = (uint32_t)s << 16; return v.f;
}

// tanh(x) = 1 - 2/(1+e^{2x}); v_rcp_f32 (~1ulp) is plenty vs bf16 storage noise.
__device__ __forceinline__ float tanh_fast(float x) {
    float e = __expf(2.0f * x);
    float r = __builtin_amdgcn_rcpf(e + 1.0f);
    return fmaf(-2.0f, r, 1.0f);
}

// Scalar casts -> compiler emits v_cvt_pk_bf16_f32 (m240: don't hand-write).
__device__ __forceinline__ uint32_t pack_bf2(float lo, float hi) {
    union { __hip_bfloat162 v; uint32_t u; } cv;
    cv.v = __halves2bfloat162(__float2bfloat16(lo), __float2bfloat16(hi));
    return cv.u;
}

__device__ __forceinline__ void load_lds16(const void* g, uint32_t* l) {
    __builtin_amdgcn_global_load_lds(
        (const __attribute__((address_space(1))) uint32_t*)g,
        (__attribute__((address_space(3))) uint32_t*)l, 16, 0, 0);
}

// ---- Prep 0 (tiny): Wb2[g][hi4][f][8] bf16 (kk=k*256+e), W2k, zero page ----
__global__ void prep_w(const float* __restrict__ conv_w,
                       const float* __restrict__ U_w, const float* __restrict__ final_w,
                       unsigned short* __restrict__ Wb2, unsigned short* __restrict__ W2k,
                       uint32_t* __restrict__ zp)
{
    int o = blockIdx.x * 256 + threadIdx.x;          // grid 1024 -> o < 262144
    {
        int kk = o & 1023, f = o >> 10;
        int e = kk & 255, k = kk >> 8;
        int g = kk >> 5, h4 = (kk >> 3) & 3, j = kk & 7;
        Wb2[((size_t)(g * 4 + h4) * 256 + f) * 8 + j] = f2bf(conv_w[f * 1024 + e * 4 + k]);
    }
    if (o < 32768) {
        int j = o & 7, c = (o >> 3) & 127, g = o >> 10;
        int k = g * 8 + j, l = c & 63;
        float v = 0.f;
        if (l < LDIM) v = (c < 64) ? U_w[l * FDIM + k] : final_w[l * FDIM + k];
        W2k[o] = f2bf(v);
    }
    if (o < 128) zp[o] = 0;
}

// ---- Prep 1: blocks 0..31 = t=4096 specials (use Wb2, coalesced); rest = embb conversion ----
__global__ __launch_bounds__(256) void prep_emb_special(
    const float* __restrict__ emb, const int* __restrict__ ids,
    const unsigned short* __restrict__ Wb2, const float* __restrict__ conv_b,
    const float* __restrict__ U_w, const float* __restrict__ final_w,
    unsigned short* __restrict__ embb, float* __restrict__ part)
{
    __shared__ float x0[256], x1[256], hsh[256], rsc[256], rtv[256];
    const int tid = threadIdx.x;
    const int idx = blockIdx.x;

    if (idx < BDIM) {
        // ---- special: position t=4096 for batch b=idx (bf16 weights from Wb2) ----
        const int b = idx;
        const int f = tid;
        {
            int id0 = ids[b * SDIM + 4094];
            int id1 = ids[b * SDIM + 4095];
            x0[f] = emb[(size_t)id0 * EDIM + f];
            x1[f] = emb[(size_t)id1 * EDIM + f];
        }
        __syncthreads();

        // H[4096][f] = sum_e w[f,e,0]*x0[e] + w[f,e,1]*x1[e]; Wb2 g<16 covers taps 0,1;
        // for fixed (g,h4), f is contiguous -> 16B/lane coalesced loads.
        float a0 = 0.f, a1 = 0.f;
        #pragma unroll
        for (int g = 0; g < 16; ++g) {
            const float* xv = (g < 8) ? x0 : x1;
            #pragma unroll
            for (int h4 = 0; h4 < 4; ++h4) {
                bf16x8v w = *(const bf16x8v*)(Wb2 + ((size_t)(g * 4 + h4) * 256 + f) * 8);
                int e0 = (g & 7) * 32 + h4 * 8;
                float s = 0.f;
                #pragma unroll
                for (int j = 0; j < 8; ++j)
                    s = fmaf(bf2f((unsigned short)w[j]), xv[e0 + j], s);
                if (g < 8) a0 += s; else a1 += s;
            }
        }
        hsh[f] = tanh_fast(conv_b[f] + a0 + a1);
        __syncthreads();

        // scores/t for 50 labels: (label, f-chunk) split, float4 loads.
        {
            const int l = tid & 63, c = tid >> 6;
            float sc = 0.f, tv = 0.f;
            if (l < LDIM) {
                const float4* uw = (const float4*)(U_w + (size_t)l * FDIM + c * 64);
                const float4* fw = (const float4*)(final_w + (size_t)l * FDIM + c * 64);
                const float4* hh = (const float4*)(hsh + c * 64);
                #pragma unroll
                for (int i = 0; i < 16; ++i) {
                    float4 h = hh[i], u = uw[i], w = fw[i];
                    sc = fmaf(h.x, u.x, fmaf(h.y, u.y, fmaf(h.z, u.z, fmaf(h.w, u.w, sc))));
                    tv = fmaf(h.x, w.x, fmaf(h.y, w.y, fmaf(h.z, w.z, fmaf(h.w, w.w, tv))));
                }
            }
            rsc[tid] = sc; rtv[tid] = tv;
        }
        __syncthreads();

        if (tid < LDIM) {
            float sc = rsc[tid] + rsc[tid + 64] + rsc[tid + 128] + rsc[tid + 192];
            float tv = rtv[tid] + rtv[tid + 64] + rtv[tid + 128] + rtv[tid + 192];
            size_t o = (((size_t)b * (NT + 1) + NT) * LDIM + tid) * 3;
            part[o] = sc; part[o + 1] = 1.0f; part[o + 2] = tv;
        }
    } else {
        // ---- streaming: embedding table fp32 -> bf16 ----
        size_t o = ((size_t)(idx - BDIM) * 256 + tid) * 8;
        if (o < (size_t)30522 * 256) {
            float4 v0 = *(const float4*)(emb + o);
            float4 v1 = *(const float4*)(emb + o + 4);
            union { unsigned short u[8]; uint4 q; } pk;
            pk.u[0] = f2bf(v0.x); pk.u[1] = f2bf(v0.y); pk.u[2] = f2bf(v0.z); pk.u[3] = f2bf(v0.w);
            pk.u[4] = f2bf(v1.x); pk.u[5] = f2bf(v1.y); pk.u[6] = f2bf(v1.z); pk.u[7] = f2bf(v1.w);
            *(uint4*)(embb + o) = pk.q;
        }
    }
}

// ---- Fused (R10 structure, best known): gather -> conv1d+tanh -> scores|t GEMM -> partials ----
__global__ __launch_bounds__(256, 2) void fused_kernel(
    const int* __restrict__ ids, const unsigned short* __restrict__ embb,
    const unsigned short* __restrict__ Wb2, const float* __restrict__ conv_b,
    const unsigned short* __restrict__ W2k, const uint32_t* __restrict__ zp,
    float* __restrict__ part)
{
    __shared__ uint32_t xs[132 * 128];   // 67,584 B: x rows 0..130, reused as H-tile

    const int tid  = threadIdx.x;
    const int lane = tid & 63;
    const int wid  = tid >> 6;
    const int b    = blockIdx.y;
    const int tile = blockIdx.x;
    const int t0   = tile * TTILE;
    const int l15  = lane & 15;
    const int hi4  = lane >> 4;
    const int q    = lane & 31;
    const int half = lane >> 5;

    // ---- stage rows 0..130 (p = t0-2+r): all ids first, then all gathers ----
    {
        int nid[17];
        #pragma unroll
        for (int j = 0; j < 17; ++j) {
            int r0 = wid * 2 + j * 8;
            int r  = r0 + half;
            int p  = t0 - 2 + r;
            nid[j] = -1;
            if (r0 < 131 && r < 131 && (unsigned)p < SDIM)
                nid[j] = ids[b * SDIM + p];
        }
        const unsigned short* zs = (const unsigned short*)zp + q * 8;
        #pragma unroll
        for (int j = 0; j < 17; ++j) {
            int r0 = wid * 2 + j * 8;
            if (r0 >= 131) continue;                 // wave-uniform guard
            int r = r0 + half;
            const unsigned short* s = (nid[j] >= 0)
                ? embb + (size_t)nid[j] * EDIM + (((uint32_t)(q * 16) ^ ((uint32_t)(r & 7) << 4)) >> 1)
                : zs;
            load_lds16(s, &xs[r0 * 128]);
        }
    }
    __syncthreads();

    // ---- Conv GEMM: wave = 64 filters (M) x 128 positions (N), K=1024 ----
    const int fbase = wid * 64;
    const unsigned short* afbase = Wb2 + (size_t)(hi4 * 256 + fbase + l15) * 8;

    f32x4 acc[4][8];
    #pragma unroll
    for (int a = 0; a < 4; ++a)
        #pragma unroll
        for (int n = 0; n < 8; ++n) acc[a][n] = (f32x4){0.f, 0.f, 0.f, 0.f};

    bf16x8v afc[4];
    #pragma unroll
    for (int a = 0; a < 4; ++a) afc[a] = *(const bf16x8v*)(afbase + a * 128);   // g=0

    #pragma unroll 1
    for (int k = 0; k < 4; ++k) {
        uint32_t bb[8];
        #pragma unroll
        for (int n = 0; n < 8; ++n) {
            int r = n * 16 + l15 + k;
            bb[n] = (uint32_t)(r * 512) ^ (uint32_t)(hi4 * 16) ^ (uint32_t)((r & 7) << 4);
        }
        const unsigned short* afg = afbase + (size_t)k * 65536;
        #pragma unroll
        for (int es = 0; es < 8; ++es) {
            // prefetch next g's A-fragments (always 4 loads in flight)
            const unsigned short* nxt = (es < 7)
                ? (afg + (size_t)(es + 1) * 8192)
                : (afbase + (size_t)((k + 1) & 3) * 65536);
            bf16x8v afn[4];
            #pragma unroll
            for (int a = 0; a < 4; ++a) afn[a] = *(const bf16x8v*)(nxt + a * 128);

            bf16x8v bfr[8];
            #pragma unroll
            for (int n = 0; n < 8; ++n)
                bfr[n] = *(const bf16x8v*)((const char*)xs + (bb[n] ^ (uint32_t)(es * 64)));

            __builtin_amdgcn_s_setprio(1);
            #pragma unroll
            for (int a = 0; a < 4; ++a)
                #pragma unroll
                for (int n = 0; n < 8; ++n)
                    acc[a][n] = __builtin_amdgcn_mfma_f32_16x16x32_bf16(afc[a], bfr[n], acc[a][n], 0, 0, 0);
            __builtin_amdgcn_s_setprio(0);

            #pragma unroll
            for (int a = 0; a < 4; ++a) afc[a] = afn[a];
        }
    }
    __syncthreads();   // all waves done reading xs

    // ---- tanh epilogue -> H-tile into LDS (same buffer), XOR-swizzled ----
    float4 cb[4];
    #pragma unroll
    for (int a = 0; a < 4; ++a)
        cb[a] = *(const float4*)(conv_b + fbase + a * 16 + hi4 * 4);
    #pragma unroll
    for (int n = 0; n < 8; ++n) {
        int tl = n * 16 + l15;
        uint32_t hb = (uint32_t)(tl * 512) ^ (uint32_t)(hi4 * 8)
                    ^ (uint32_t)(fbase * 2) ^ (uint32_t)((tl & 7) << 4);
        #pragma unroll
        for (int a = 0; a < 4; ++a) {
            f32x4 d = acc[a][n];
            uint2 pk;
            pk.x = pack_bf2(tanh_fast(d[0] + cb[a].x), tanh_fast(d[1] + cb[a].y));
            pk.y = pack_bf2(tanh_fast(d[2] + cb[a].z), tanh_fast(d[3] + cb[a].w));
            *(uint2*)((char*)xs + (hb ^ (uint32_t)(a * 32))) = pk;
        }
    }
    __syncthreads();

    // ---- P GEMM: 128 s-rows x 32 cols per wave (cbase..+15 scores, +64 t), K=256 ----
    const int cbase = wid * 16;
    f32x4 p2[8][2];
    #pragma unroll
    for (int m = 0; m < 8; ++m) { p2[m][0] = (f32x4){0,0,0,0}; p2[m][1] = (f32x4){0,0,0,0}; }

    uint32_t pb[8];
    #pragma unroll
    for (int m = 0; m < 8; ++m) {
        int sl = m * 16 + l15;
        pb[m] = (uint32_t)(sl * 512) ^ (uint32_t)(hi4 * 16) ^ (uint32_t)((sl & 7) << 4);
    }
    const unsigned short* wp0 = W2k + (size_t)(hi4 * 128 + cbase + l15) * 8;

    #pragma unroll
    for (int step = 0; step < 8; ++step) {
        bf16x8v ha[8], w2[2];
        #pragma unroll
        for (int m = 0; m < 8; ++m)
            ha[m] = *(const bf16x8v*)((const char*)xs + (pb[m] ^ (uint32_t)(step * 64)));
        w2[0] = *(const bf16x8v*)(wp0 + step * 4096);
        w2[1] = *(const bf16x8v*)(wp0 + 512 + step * 4096);
        __builtin_amdgcn_s_setprio(1);
        #pragma unroll
        for (int m = 0; m < 8; ++m) {
            p2[m][0] = __builtin_amdgcn_mfma_f32_16x16x32_bf16(ha[m], w2[0], p2[m][0], 0, 0, 0);
            p2[m][1] = __builtin_amdgcn_mfma_f32_16x16x32_bf16(ha[m], w2[1], p2[m][1], 0, 0, 0);
        }
        __builtin_amdgcn_s_setprio(0);
    }

    // ---- Lane-local online-softmax partials (all 128 rows valid) ----
    float mx = -1e30f;
    #pragma unroll
    for (int m = 0; m < 8; ++m)
        #pragma unroll
        for (int i = 0; i < 4; ++i)
            mx = fmaxf(mx, p2[m][0][i]);
    float se = 0.f, st = 0.f;
    #pragma unroll
    for (int m = 0; m < 8; ++m)
        #pragma unroll
        for (int i = 0; i < 4; ++i) {
            float e = __expf(p2[m][0][i] - mx);
            se += e;
            st += e * p2[m][1][i];
        }
    #pragma unroll
    for (int d = 16; d <= 32; d <<= 1) {
        float mo  = __shfl_xor(mx, d);
        float seo = __shfl_xor(se, d);
        float sto = __shfl_xor(st, d);
        float M  = fmaxf(mx, mo);
        float w0 = __expf(mx - M), w1 = __expf(mo - M);
        se = se * w0 + seo * w1;
        st = st * w0 + sto * w1;
        mx = M;
    }
    if (lane < 16) {
        int l = cbase + l15;
        if (l < LDIM) {
            size_t o = (((size_t)b * (NT + 1) + tile) * LDIM + l) * 3;
            part[o] = mx; part[o + 1] = se; part[o + 2] = st;
        }
    }
}

// ---- Final: merge 33 partial chunks -> logits ----
__global__ __launch_bounds__(64) void final_kernel(
    const float* __restrict__ part, const float* __restrict__ final_b,
    float* __restrict__ out)
{
    int b = blockIdx.x, l = threadIdx.x;
    if (l >= LDIM) return;
    float mx = -1e30f, se = 0.f, st = 0.f;
    for (int c = 0; c <= NT; ++c) {
        size_t o = (((size_t)b * (NT + 1) + c) * LDIM + l) * 3;
        float mo = part[o], seo = part[o + 1], sto = part[o + 2];
        float M  = fmaxf(mx, mo);
        float w0 = __expf(mx - M), w1 = __expf(mo - M);
        se = se * w0 + seo * w1;
        st = st * w0 + sto * w1;
        mx = M;
    }
    out[b * LDIM + l] = st / se + final_b[l];
}

extern "C" void kernel_launch(void* const* d_in, const int* in_sizes, int n_in,
                              void* d_out, int out_size, void* d_ws, size_t ws_size,
                              hipStream_t stream)
{
    const int*   ids     = (const int*)d_in[0];
    const float* emb     = (const float*)d_in[1];
    const float* conv_w  = (const float*)d_in[2];
    const float* conv_b  = (const float*)d_in[3];
    const float* U_w     = (const float*)d_in[4];
    const float* final_w = (const float*)d_in[5];
    const float* final_b = (const float*)d_in[6];

    char* ws = (char*)d_ws;
    size_t offE  = 0;
    size_t szE   = (size_t)30522 * 256 * 2;          // 15,627,264 B
    size_t offWb = offE + szE;
    size_t szWb  = 256 * 1024 * 2;                   // 524,288 B
    size_t offW2 = offWb + szWb;
    size_t szW2  = 32768 * 2;                        // 65,536 B
    size_t offZ  = offW2 + szW2;
    size_t szZ   = 512;
    size_t offP  = offZ + szZ;                       // 32*33*50*3 fp32 = 633,600 B

    unsigned short* embb = (unsigned short*)(ws + offE);
    unsigned short* Wb2  = (unsigned short*)(ws + offWb);
    unsigned short* W2k  = (unsigned short*)(ws + offW2);
    uint32_t*       zp   = (uint32_t*)(ws + offZ);
    float*          prt  = (float*)(ws + offP);

    prep_w<<<1024, 256, 0, stream>>>(conv_w, U_w, final_w, Wb2, W2k, zp);
    prep_emb_special<<<3816 + BDIM, 256, 0, stream>>>(emb, ids, Wb2, conv_b,
                                                      U_w, final_w, embb, prt);
    fused_kernel<<<dim3(NT, BDIM), 256, 0, stream>>>(ids, embb, Wb2, conv_b, W2k, zp, prt);
    final_kernel<<<BDIM, 64, 0, stream>>>(prt, final_b, (float*)d_out);
}